// Round 8
// baseline (285.713 us; speedup 1.0000x reference)
//
#include <hip/hip_runtime.h>
#include <hip/hip_bf16.h>
#include <hip/hip_fp16.h>
#include <math.h>

#define B_TOTAL 8192
#define NN      82
#define HH      10
#define OUTC    5
#define TSTEP   3
#define NB      3            // batches per block: 246/256 GRU lanes active (the r5 lesson)
#define THREADS 256
#define KP      96           // padded adjacency dim (3 x 32)
#define RS      10           // packed Xt row stride per batch (r3/r5-proven overlap trick)
#define NROWS   36           // 30 data rows + 6 zeroed overlap rows
#define XS      104          // Xt row stride in bf16 (208 B)
#define UTS     248          // uT pair-row stride in half2 slots (>= NB*NN = 246)

// LDS (bytes) — NO aliasing (uT is fp16, half the size -> everything fits 5 blocks/CU):
//   [0      .. 7488)   XtH  bf16[36][104]
//   [7488   .. 14976)  XtL  bf16[36][104]
//   [14976  .. 24896)  uT16 half[10 pairrows][248 slots][2]  (rows 0-4 in, 5-9 out)
//   [24896  .. 28736)  wS   float[960]
#define XTL_OFF 7488
#define UT_OFF  14976
#define WS_OFF  24896
#define SMEM_BYTES 28736     // -> 5 blocks/CU (28.7 KB x 5 = 143.7 KB <= 160 KB)

// wS offsets (floats)
#define W3W 0
#define W4W 200
#define W5W 400
#define W3U 600
#define W5U 700
#define WOUT 800
#define B3W 900
#define B4W 910
#define B5W 920
#define B3U 930
#define B5U 940
#define BOUT 950

typedef __bf16 bf16x8 __attribute__((ext_vector_type(8)));
typedef float  f32x4  __attribute__((ext_vector_type(4)));
typedef float  f32x2  __attribute__((ext_vector_type(2)));

__device__ __forceinline__ float sigmoid_(float x) {
    return 1.0f / (1.0f + __expf(-x));
}
__device__ __forceinline__ float tanh_(float x) {
    float e = __expf(2.0f * x);
    return 1.0f - 2.0f / (e + 1.0f);
}
__device__ __forceinline__ f32x2 ld2(const float* p) {       // 8B-aligned pair (LDS)
    return *reinterpret_cast<const f32x2*>(p);
}
__device__ __forceinline__ f32x2 fma2(f32x2 a, f32x2 b, f32x2 c) {
    return __builtin_elementwise_fma(a, b, c);               // -> v_pk_fma_f32
}

// d_ws: EXACT r0-r5 proven 73,728 B (adjP hi/lo only; r6's overflow lesson).
__global__ void prep_adj_kernel(const float* __restrict__ in_adj,
                                const float* __restrict__ out_adj,
                                __hip_bfloat16* __restrict__ adjP) {
    int idx = blockIdx.x * blockDim.x + threadIdx.x;
    if (idx < 2 * KP * KP) {
        int a   = idx / (KP * KP);
        int rem = idx - a * (KP * KP);
        int i = rem / KP;
        int j = rem - i * KP;
        float v = 0.0f;
        if (i < NN && j < NN) v = (a == 0) ? in_adj[i * NN + j] : out_adj[i * NN + j];
        __hip_bfloat16 hi = __float2bfloat16(v);
        __hip_bfloat16 lo = __float2bfloat16(v - __bfloat162float(hi));
        adjP[idx]               = hi;
        adjP[2 * KP * KP + idx] = lo;
    }
}

// (256,5): arch cap 51 V + ~51 AGPR. Demand: agg ~45 (acc 12 + one k-slice of
// frags), GRU ~60 (overflow -> cheap AGPR moves, r5-proven clean pattern).
// NB=3 keeps GRU wave-issue at the r0 level; fp16 uT removes the LDS blocker.
extern "C" __global__ __launch_bounds__(THREADS, 5)
void ggnn_kernel(const float* __restrict__ x,
                 const __hip_bfloat16* __restrict__ adjP,
                 const float* __restrict__ w3w, const float* __restrict__ b3w,
                 const float* __restrict__ w3u, const float* __restrict__ b3u,
                 const float* __restrict__ w4w, const float* __restrict__ b4w,
                 const float* __restrict__ w5w, const float* __restrict__ b5w,
                 const float* __restrict__ w5u, const float* __restrict__ b5u,
                 const float* __restrict__ wout, const float* __restrict__ bout,
                 float* __restrict__ out0, float* __restrict__ out_fn)
{
    __shared__ __align__(16) unsigned char smem[SMEM_BYTES];
    __hip_bfloat16* XtH = reinterpret_cast<__hip_bfloat16*>(smem);
    __hip_bfloat16* XtL = reinterpret_cast<__hip_bfloat16*>(smem + XTL_OFF);
    __half*         uH  = reinterpret_cast<__half*>(smem + UT_OFF);
    float*          wS  = reinterpret_cast<float*>(smem + WS_OFF);

    const int t     = threadIdx.x;
    const int bbase = blockIdx.x * NB;
    const int bl    = t / NN;            // 0..2 GRU-active, 3 = spare lanes
    const int node  = t - bl * NN;
    const bool act  = (bl < NB) && (bbase + bl < B_TOTAL);
    const int b     = bbase + bl;

    const int lane = t & 63;
    const int w    = t >> 6;             // wave id 0..3
    const int lo16 = lane & 15;
    const int quad = lane >> 4;

    // ---- zero-init the whole Xt region (guarantees overlap rows 30..35 and
    //      K-pad cols are 0.0 forever -> no NaN into MFMA) ----
    for (int i = t; i < UT_OFF / 16; i += THREADS)
        reinterpret_cast<f32x4*>(smem)[i] = (f32x4){0, 0, 0, 0};

    // ---- stage weights into LDS (coalesced; once per block) ----
    for (int i = t; i < 200; i += THREADS) {
        wS[W3W + i] = w3w[i];
        wS[W4W + i] = w4w[i];
        wS[W5W + i] = w5w[i];
    }
    if (t < 100) {
        wS[W3U + t]  = w3u[t];
        wS[W5U + t]  = w5u[t];
        wS[WOUT + t] = wout[t];
    }
    if (t < 10) {
        wS[B3W + t] = b3w[t];
        wS[B4W + t] = b4w[t];
        wS[B5W + t] = b5w[t];
        wS[B3U + t] = b3u[t];
        wS[B5U + t] = b5u[t];
    }
    if (t < OUTC) wS[BOUT + t] = bout[t];

    __syncthreads();   // zero-fill visible before cross-thread scatter

    // ---- per-wave (ntile,adj) combo mapping: B streamed from L2 ----
    int ntile_c[3], adj_c[3], Boff[3];
    #pragma unroll
    for (int c = 0; c < 3; ++c) {
        int co = w * 3 + c;              // 12 combos = 6 ntiles x 2 adj
        int nt = co >> 1;
        int ad = co & 1;
        ntile_c[c] = nt;
        adj_c[c]   = ad;
        Boff[c] = ad * KP * KP + (nt * 16 + lo16) * KP + quad * 8;
    }

    // ---- initial fill of XtH/XtL from x (coalesced read); rows = b_l*10 + h ----
    for (int idx = t; idx < NB * NN * HH; idx += THREADS) {
        int b_l = idx / (NN * HH);
        int rem = idx - b_l * (NN * HH);
        int j   = rem / HH;
        int h   = rem - j * HH;
        size_t g = (size_t)bbase * NN * HH + idx;
        float v = (g < (size_t)B_TOTAL * NN * HH) ? x[g] : 0.0f;
        __hip_bfloat16 hi = __float2bfloat16(v);
        __hip_bfloat16 lo = __float2bfloat16(v - __bfloat162float(hi));
        XtH[(b_l * RS + h) * XS + j] = hi;
        XtL[(b_l * RS + h) * XS + j] = lo;
    }

    // ---- per-thread GRU state fn (as f32x2 pairs) from x ----
    f32x2 fn2[5];
    if (act) {
        const float* xr = x + ((size_t)b * NN + node) * HH;
        #pragma unroll
        for (int p = 0; p < 5; ++p) {
            float2 v = reinterpret_cast<const float2*>(xr)[p];
            fn2[p].x = v.x; fn2[p].y = v.y;
        }
    }

    #pragma unroll 1
    for (int step = 0; step < TSTEP; ++step) {
        __syncthreads();   // [A] Xt (and at step 0: init) fully written

        // ---- AGG: A from LDS, B streamed from L2; immediate C-write to uT16
        //      (uT does NOT alias Xt -> r0's simple 2-barrier loop). ----
        #pragma unroll 1
        for (int mtile = 0; mtile < NB; ++mtile) {
            f32x4 acc[3] = {{0,0,0,0}, {0,0,0,0}, {0,0,0,0}};
            #pragma unroll 1
            for (int k = 0; k < 3; ++k) {
                bf16x8 ah = *reinterpret_cast<const bf16x8*>(&XtH[(mtile * RS + lo16) * XS + quad * 8 + k * 32]);
                bf16x8 al = *reinterpret_cast<const bf16x8*>(&XtL[(mtile * RS + lo16) * XS + quad * 8 + k * 32]);
                #pragma unroll
                for (int c = 0; c < 3; ++c) {
                    const __hip_bfloat16* bp = adjP + Boff[c] + k * 32;
                    bf16x8 bh  = *reinterpret_cast<const bf16x8*>(bp);
                    bf16x8 bl_ = *reinterpret_cast<const bf16x8*>(bp + 2 * KP * KP);
                    acc[c] = __builtin_amdgcn_mfma_f32_16x16x32_bf16(ah, bh,  acc[c], 0, 0, 0);
                    acc[c] = __builtin_amdgcn_mfma_f32_16x16x32_bf16(al, bh,  acc[c], 0, 0, 0);
                    acc[c] = __builtin_amdgcn_mfma_f32_16x16x32_bf16(ah, bl_, acc[c], 0, 0, 0);
                }
            }
            // C element (reg r): h = quad*4+r, col i = ntile*16+lo16 (h<10, i<82).
            // Store fp16: pairrow = adj*5 + h/2, half-sel = h&1.
            #pragma unroll
            for (int c = 0; c < 3; ++c) {
                int i = ntile_c[c] * 16 + lo16;
                if (i < NN) {
                    int col   = mtile * NN + i;
                    int pbase = adj_c[c] * 5;
                    if (quad < 2) {
                        #pragma unroll
                        for (int r = 0; r < 4; ++r) {
                            int h = quad * 4 + r;
                            uH[((pbase + (h >> 1)) * UTS + col) * 2 + (h & 1)] = __float2half(acc[c][r]);
                        }
                    } else if (quad == 2) {
                        uH[((pbase + 4) * UTS + col) * 2 + 0] = __float2half(acc[c][0]);  // h=8
                        uH[((pbase + 4) * UTS + col) * 2 + 1] = __float2half(acc[c][1]);  // h=9
                    }
                }
            }
        }

        __syncthreads();   // [B] uT fully written

        // ---- per-thread GRU (r5-proven form; av via half2 -> float) ----
        if (act) {
            f32x2 av2[10];
            #pragma unroll
            for (int p = 0; p < 5; ++p) {
                __half2 hin  = *reinterpret_cast<const __half2*>(uH + (p * UTS + t) * 2);
                __half2 hout = *reinterpret_cast<const __half2*>(uH + ((5 + p) * UTS + t) * 2);
                float2 fi = __half22float2(hin);
                float2 fo = __half22float2(hout);
                av2[p].x = fi.x;     av2[p].y = fi.y;
                av2[5 + p].x = fo.x; av2[5 + p].y = fo.y;
            }

            float zv[HH];
            f32x2 rf2[5];
            #pragma unroll
            for (int h = 0; h < HH; ++h) {
                // u3h inlined (shared by zv and rv — reference bug reusing w3u)
                f32x2 su = {0.0f, 0.0f};
                #pragma unroll
                for (int p = 0; p < 5; ++p)
                    su = fma2(ld2(&wS[W3U + h * HH + 2 * p]), fn2[p], su);
                float u3h = wS[B3U + h] + su.x + su.y;

                f32x2 z2 = {0.0f, 0.0f}, r2 = {0.0f, 0.0f};
                #pragma unroll
                for (int p = 0; p < 10; ++p) {
                    z2 = fma2(ld2(&wS[W3W + h * 20 + 2 * p]), av2[p], z2);
                    r2 = fma2(ld2(&wS[W4W + h * 20 + 2 * p]), av2[p], r2);
                }
                zv[h] = sigmoid_(wS[B3W + h] + z2.x + z2.y + u3h);
                float rv = sigmoid_(wS[B4W + h] + r2.x + r2.y + u3h);
                float fnh = (h & 1) ? fn2[h >> 1].y : fn2[h >> 1].x;
                if (h & 1) rf2[h >> 1].y = rv * fnh; else rf2[h >> 1].x = rv * fnh;
            }

            #pragma unroll
            for (int h = 0; h < HH; ++h) {
                f32x2 s2 = {0.0f, 0.0f};
                #pragma unroll
                for (int p = 0; p < 10; ++p)
                    s2 = fma2(ld2(&wS[W5W + h * 20 + 2 * p]), av2[p], s2);
                #pragma unroll
                for (int p = 0; p < 5; ++p)
                    s2 = fma2(ld2(&wS[W5U + h * HH + 2 * p]), rf2[p], s2);
                float hv = tanh_(wS[B5W + h] + wS[B5U + h] + s2.x + s2.y);
                float fnh = (h & 1) ? fn2[h >> 1].y : fn2[h >> 1].x;
                fnh = fnh + zv[h] * (hv - fnh);
                if (h & 1) fn2[h >> 1].y = fnh; else fn2[h >> 1].x = fnh;
            }

            // publish new state into Xt (hi/lo) for next step's aggregation.
            // Safe vs other waves: everyone passed [B], next agg read is after [A].
            if (step < TSTEP - 1) {
                #pragma unroll
                for (int h = 0; h < HH; ++h) {
                    float fnh = (h & 1) ? fn2[h >> 1].y : fn2[h >> 1].x;
                    __hip_bfloat16 hi = __float2bfloat16(fnh);
                    __hip_bfloat16 lo = __float2bfloat16(fnh - __bfloat162float(hi));
                    XtH[(bl * RS + h) * XS + node] = hi;
                    XtL[(bl * RS + h) * XS + node] = lo;
                }
            }
        }
    }

    // ---- epilogue: out0 = tanh([fn, x] @ wout^T + bout), out_fn = fn ----
    if (act) {
        size_t row = (size_t)b * NN + node;
        const float* xr = x + row * HH;
        f32x2 xi2[5];
        #pragma unroll
        for (int p = 0; p < 5; ++p) {
            float2 v = reinterpret_cast<const float2*>(xr)[p];
            xi2[p].x = v.x; xi2[p].y = v.y;
        }

        #pragma unroll
        for (int c = 0; c < OUTC; ++c) {
            f32x2 s2 = {0.0f, 0.0f};
            #pragma unroll
            for (int p = 0; p < 5; ++p) {
                s2 = fma2(ld2(&wS[WOUT + c * 20 + 2 * p]),      fn2[p], s2);
                s2 = fma2(ld2(&wS[WOUT + c * 20 + 10 + 2 * p]), xi2[p], s2);
            }
            out0[row * OUTC + c] = tanh_(wS[BOUT + c] + s2.x + s2.y);
        }
        #pragma unroll
        for (int p = 0; p < 5; ++p) {
            reinterpret_cast<float2*>(out_fn + row * HH)[p] =
                make_float2(fn2[p].x, fn2[p].y);
        }
    }
}

extern "C" void kernel_launch(void* const* d_in, const int* in_sizes, int n_in,
                              void* d_out, int out_size, void* d_ws, size_t ws_size,
                              hipStream_t stream) {
    const float* x       = (const float*)d_in[0];
    const float* in_adj  = (const float*)d_in[1];
    const float* out_adj = (const float*)d_in[2];
    const float* w3w = (const float*)d_in[3];
    const float* b3w = (const float*)d_in[4];
    const float* w3u = (const float*)d_in[5];
    const float* b3u = (const float*)d_in[6];
    const float* w4w = (const float*)d_in[7];
    const float* b4w = (const float*)d_in[8];
    const float* w5w = (const float*)d_in[9];
    const float* b5w = (const float*)d_in[10];
    const float* w5u = (const float*)d_in[11];
    const float* b5u = (const float*)d_in[12];
    const float* wout = (const float*)d_in[13];
    const float* bout = (const float*)d_in[14];

    __hip_bfloat16* adjP = (__hip_bfloat16*)d_ws;   // 4*96*96*2 = 73,728 B (r0-5 proven)
    float* out0   = (float*)d_out;
    float* out_fn = out0 + (size_t)B_TOTAL * NN * OUTC;

    prep_adj_kernel<<<(2 * KP * KP + 255) / 256, 256, 0, stream>>>(in_adj, out_adj, adjP);

    int grid = (B_TOTAL + NB - 1) / NB;             // 2731
    ggnn_kernel<<<grid, THREADS, 0, stream>>>(
        x, adjP, w3w, b3w, w3u, b3u, w4w, b4w, w5w, b5w, w5u, b5u,
        wout, bout, out0, out_fn);
}